// Round 11
// baseline (406.650 us; speedup 1.0000x reference)
//
#include <hip/hip_runtime.h>
#include <cstddef>

// Problem shape (fixed): N=50000, K=16, C_IN=128, C2=256, C_OUT=128.
#define C_IN  128
#define C2    256
#define C_OUT 128
#define KNBR  16
#define PTS   32     // points per gather_out block

typedef unsigned short u16;
typedef __attribute__((ext_vector_type(8))) short bf16x8;   // 8 bf16 (4 VGPRs)
typedef __attribute__((ext_vector_type(4))) float f32x4;

__device__ __forceinline__ float bf2f(u16 h) {
    return __uint_as_float(((unsigned int)h) << 16);
}
__device__ __forceinline__ u16 f2bf(float x) {
    unsigned int u = __float_as_uint(x);
    return (u16)((u + 0x7fffu + ((u >> 16) & 1u)) >> 16);
}

// Channel permutation: weight row rho = 16j+4q+p is STORED at packed position
// sigma(rho) = 32*(j>>1) + 8q + 4*(j&1) + p. Permuting W rows by sigma in prep
// makes the mlp lane's natural burst-store layout equal STANDARD channel order.
__device__ __forceinline__ int sigma_p(int n) {
    return ((n >> 5) << 5) | (((n >> 2) & 3) << 3) | (((n >> 4) & 1) << 2) | (n & 3);
}

// Transpose + convert weights to bf16, n-major [N][K] with sigma-permuted rows
// for W1t/Wst; fold BN params (SoA, standard channel order).
__global__ void prep_k(const float* __restrict__ W1, const float* __restrict__ Ws,
                       const float* __restrict__ Wm, const float* __restrict__ b1,
                       const float* __restrict__ gamma, const float* __restrict__ beta,
                       const float* __restrict__ mean, const float* __restrict__ var,
                       u16* __restrict__ W1t, u16* __restrict__ Wst,
                       u16* __restrict__ Wmt, float* __restrict__ bnp)
{
    const int n = blockIdx.x, t = threadIdx.x;
    if (blockIdx.y == 0) {
        if (t < 128) W1t[n * 128 + t] = f2bf(W1[t * 256 + sigma_p(n)]);
    } else if (blockIdx.y == 1) {
        Wst[n * 256 + t] = f2bf(Ws[t * 256 + sigma_p(n)]);
    } else if (blockIdx.y == 2) {
        if (n < 128) Wmt[n * 256 + t] = f2bf(Wm[t * 128 + n]);
    } else if (n == 0) {
        // x = (relu(z+b1)-mu)*iv + be = relu(z+c1)*c2 + c3, SoA planes
        float iv = gamma[t] * rsqrtf(var[t] + 1e-5f);
        bnp[t]       = b1[t];
        bnp[256 + t] = iv;
        bnp[512 + t] = beta[t] - mean[t] * iv;
    }
}

// ---------------------------------------------------------------------------
// LESSONS ENCODED:
//  R7:  accumulator arrays indexed by non-unrolled loop vars spill to scratch.
//  R12: gather random-read fabric ~3.4 TB/s at full occupancy; FETCH ~370 MB
//       structural. NEVER split the grid below residency (R6: -40 us).
//  R14: launch_bounds cap below per-phase live state => silent scratch spill.
//  R18: OPERAND SWAP: mfma(W_frag, F_frag) puts points in lane&15, channels
//       in (lane>>4)*4+p -> per-point channel-contiguous output chunks.
//  R21 (this round): THREE store-layout fixes (2B/8B/16B-sector-burst) left
//       WRITE~200MB FETCH~150MB dur~140us IDENTICAL => traffic was never the
//       packed stores. VGPR_Count pinned at EXACTLY 128 every time = default
//       __launch_bounds__(512) cap; live state (xb 32 + ob 32 + acc + wa
//       pipeline + addr ~ 115-150) >= cap => silent scratch spill; ~160B/lane
//       x2 x 3125 tiles ~ matches the excess ~175MB WRITE / ~120MB FETCH.
//       R7's "RMW" diagnosis mis-read a SPILL signature. Fix: (512,2) ->
//       cap 256. Minimal diff vs R10 = clean A/B of the spill theory.
// packed row (512 u16): [ey 256 | x 256] halves, standard channel order.
// ---------------------------------------------------------------------------

// mlp1: x = BN(relu(F @ W1 + b1)) -> packed x-half.
// W1t(sigma) in LDS once (69.6 KB, 512 thr -> 2 blocks/CU, 16 waves/CU).
// Zero barriers in the loop; 16 points per wave-tile; burst 64B-sector stores.
__global__ __launch_bounds__(512, 2)
void mlp1_k(const float* __restrict__ F, const u16* __restrict__ W1t,
            const float* __restrict__ bnp, u16* __restrict__ packed, int N)
{
    __shared__ u16 Wl[256 * 136];   // 69.6 KB, stride 136 (2-way banks)
    const int tid = threadIdx.x;
    const int w = tid >> 6, l = tid & 63, q = l >> 4, r = l & 15;

    #pragma unroll
    for (int i = 0; i < 8; i++) {          // 4096 uint4, 8/thread
        int idx = tid + i * 512;
        int row = idx >> 4, g = (idx & 15) * 8;
        *(uint4*)&Wl[row * 136 + g] = *(const uint4*)(W1t + row * 128 + g);
    }
    __syncthreads();   // the only barrier

    const int nwt = (N + 15) >> 4;          // 3125 wave-tiles
    const int nw = gridDim.x * 8;
    for (int wt = blockIdx.x * 8 + w; wt < nwt; wt += nw) {
        const int base = wt * 16;
        const int gr = min(base + r, N - 1);
        // F as B-operand: lane(q,r) holds B[k=q*8+e][n=r] = F[base+r][k]
        bf16x8 fb[4];
        #pragma unroll
        for (int kt = 0; kt < 4; kt++) {
            const float* s = F + (size_t)gr * C_IN + kt * 32 + q * 8;
            float4 v0 = *(const float4*)s;
            float4 v1 = *(const float4*)(s + 4);
            bf16x8 a;
            a[0] = (short)f2bf(v0.x); a[1] = (short)f2bf(v0.y);
            a[2] = (short)f2bf(v0.z); a[3] = (short)f2bf(v0.w);
            a[4] = (short)f2bf(v1.x); a[5] = (short)f2bf(v1.y);
            a[6] = (short)f2bf(v1.z); a[7] = (short)f2bf(v1.w);
            fb[kt] = a;
        }
        const bool ok = (base + r) < N;
        uint2 ob[16];                        // 32 VGPR output buffer
        #pragma unroll
        for (int j = 0; j < 16; j++) {
            f32x4 acc = {0.f, 0.f, 0.f, 0.f};
            #pragma unroll
            for (int kt = 0; kt < 4; kt++) {
                bf16x8 wa = *(const bf16x8*)&Wl[(j * 16 + r) * 136 + kt * 32 + q * 8];
                acc = __builtin_amdgcn_mfma_f32_16x16x32_bf16(wa, fb[kt], acc, 0, 0, 0);
            }
            // standard channel of value p = 32*(j>>1) + 8q + 4*(j&1) + p
            const int c0p = ((j >> 1) << 5) + (q << 3) + ((j & 1) << 2);
            const float4 b1v = *(const float4*)&bnp[c0p];
            const float4 ivv = *(const float4*)&bnp[256 + c0p];
            const float4 bev = *(const float4*)&bnp[512 + c0p];
            u16 h0 = f2bf(fmaxf(acc[0] + b1v.x, 0.f) * ivv.x + bev.x);
            u16 h1 = f2bf(fmaxf(acc[1] + b1v.y, 0.f) * ivv.y + bev.y);
            u16 h2 = f2bf(fmaxf(acc[2] + b1v.z, 0.f) * ivv.z + bev.z);
            u16 h3 = f2bf(fmaxf(acc[3] + b1v.w, 0.f) * ivv.w + bev.w);
            ob[j].x = (unsigned)h0 | ((unsigned)h1 << 16);
            ob[j].y = (unsigned)h2 | ((unsigned)h3 << 16);
        }
        if (ok) {   // burst: 8 x 16B/lane; 4 q-lanes = full 64B sector per row
            u16* rowp = packed + (size_t)(base + r) * 512 + 256 + q * 8;
            #pragma unroll
            for (int s = 0; s < 8; s++) {
                uint4 v;
                v.x = ob[2 * s].x;     v.y = ob[2 * s].y;
                v.z = ob[2 * s + 1].x; v.w = ob[2 * s + 1].y;
                *(uint4*)(rowp + s * 32) = v;
            }
        }
    }
}

// mlp2: ey = exp(x @ Ws) -> packed ey-half. Same structure; Wst(sigma) in LDS
// (132 KB, 1 block/CU of 8 independent waves); x-half read back coalesced.
__global__ __launch_bounds__(512, 2)
void mlp2_k(const u16* __restrict__ Wst, u16* __restrict__ packed, int N)
{
    __shared__ u16 Wsl[256 * 264];  // 132 KB, stride 264 (2-way banks)
    const int tid = threadIdx.x;
    const int w = tid >> 6, l = tid & 63, q = l >> 4, r = l & 15;

    #pragma unroll
    for (int i = 0; i < 16; i++) {         // 8192 uint4, 16/thread
        int idx = tid + i * 512;
        int row = idx >> 5, g = (idx & 31) * 8;
        *(uint4*)&Wsl[row * 264 + g] = *(const uint4*)(Wst + row * 256 + g);
    }
    __syncthreads();   // the only barrier

    const int nwt = (N + 15) >> 4;          // 3125 wave-tiles
    const int nw = gridDim.x * 8;
    for (int wt = blockIdx.x * 8 + w; wt < nwt; wt += nw) {
        const int base = wt * 16;
        const int gr = min(base + r, N - 1);
        // x as B-operand: lane(q,r) holds B[k=q*8+e][n=r] = x[base+r][k]
        bf16x8 xb[8];
        #pragma unroll
        for (int kt = 0; kt < 8; kt++)
            xb[kt] = *(const bf16x8*)(packed + (size_t)gr * 512 + 256 + kt * 32 + q * 8);
        const bool ok = (base + r) < N;
        uint2 ob[16];
        #pragma unroll
        for (int j = 0; j < 16; j++) {
            f32x4 acc = {0.f, 0.f, 0.f, 0.f};
            #pragma unroll
            for (int kt = 0; kt < 8; kt++) {
                bf16x8 wa = *(const bf16x8*)&Wsl[(j * 16 + r) * 264 + kt * 32 + q * 8];
                acc = __builtin_amdgcn_mfma_f32_16x16x32_bf16(wa, xb[kt], acc, 0, 0, 0);
            }
            u16 h0 = f2bf(__expf(acc[0]));
            u16 h1 = f2bf(__expf(acc[1]));
            u16 h2 = f2bf(__expf(acc[2]));
            u16 h3 = f2bf(__expf(acc[3]));
            ob[j].x = (unsigned)h0 | ((unsigned)h1 << 16);
            ob[j].y = (unsigned)h2 | ((unsigned)h3 << 16);
        }
        if (ok) {
            u16* rowp = packed + (size_t)(base + r) * 512 + q * 8;
            #pragma unroll
            for (int s = 0; s < 8; s++) {
                uint4 v;
                v.x = ob[2 * s].x;     v.y = ob[2 * s].y;
                v.z = ob[2 * s + 1].x; v.w = ob[2 * s + 1].y;
                *(uint4*)(rowp + s * 32) = v;
            }
        }
    }
}

// Fused gather + attentive pool + output GEMM. 32 points/block, 4 waves.
// Phase 1: each wave pools 8 points; 16 rows in TWO passes of 8 neighbors
//          (ey-half + x-half ushort4 loads, 32-VGPR payload -> no scratch).
// Phase 2: out[32 x 128] = feat @ Wmt + bm, B direct from L2-resident Wmt;
//          fp32 epilogue staging ALIASES the feat buffer.
// Single 1563-block dispatch (R12: never split below residency capacity).
__global__ __launch_bounds__(256, 5)
void gather_out_k(const u16* __restrict__ packed, const int* __restrict__ nidx,
                  const u16* __restrict__ Bt, const float* __restrict__ bias,
                  float* __restrict__ Cf, int N)
{
    __shared__ int rows[PTS * KNBR];                 // 2 KB
    __shared__ __align__(16) u16 fsm[PTS * 264];     // feat bf16 / STF fp32 alias

    const int tid = threadIdx.x;
    const int w = tid >> 6, l = tid & 63, q = l >> 4, r = l & 15;
    const int m0 = blockIdx.x * PTS;

    // stage neighbor indices: PTS*16 = 512 ints, 2/thread
    #pragma unroll
    for (int i = 0; i < 2; i++) {
        int idx = tid + i * 256;
        int n = m0 + (idx >> 4);
        rows[idx] = (n < N) ? nidx[n * KNBR + (idx & 15)] : 0;
    }
    __syncthreads();

    // ---- phase 1: gather + pool, wave w -> points w*8 .. w*8+7 ----
    #pragma unroll 1
    for (int ip = 0; ip < 8; ip++) {
        const int pl = w * 8 + ip;
        float num[4] = {0.f, 0.f, 0.f, 0.f};
        float den[4] = {0.f, 0.f, 0.f, 0.f};
        #pragma unroll 1
        for (int hf = 0; hf < 2; hf++) {
            ushort4 eh[8], xh[8];
            #pragma unroll
            for (int k = 0; k < 8; k++) {
                const size_t b = (size_t)rows[pl * KNBR + hf * 8 + k] * 512;
                eh[k] = *(const ushort4*)(packed + b + l * 4);
                xh[k] = *(const ushort4*)(packed + b + 256 + l * 4);
            }
            #pragma unroll
            for (int k = 0; k < 8; k++) {
                float e0 = bf2f(eh[k].x), e1 = bf2f(eh[k].y);
                float e2 = bf2f(eh[k].z), e3 = bf2f(eh[k].w);
                den[0] += e0; den[1] += e1; den[2] += e2; den[3] += e3;
                num[0] = fmaf(e0, bf2f(xh[k].x), num[0]);
                num[1] = fmaf(e1, bf2f(xh[k].y), num[1]);
                num[2] = fmaf(e2, bf2f(xh[k].z), num[2]);
                num[3] = fmaf(e3, bf2f(xh[k].w), num[3]);
            }
        }
        ushort4 o;
        o.x = f2bf(num[0] / den[0]); o.y = f2bf(num[1] / den[1]);
        o.z = f2bf(num[2] / den[2]); o.w = f2bf(num[3] / den[3]);
        *(ushort4*)&fsm[pl * 264 + l * 4] = o;   // rows >= N: garbage, never stored
    }
    __syncthreads();   // feat tile complete

    // ---- phase 2: out GEMM, wave grid 2M x 2N; B direct from L2 ----
    const int wm = w & 1, wn = w >> 1;
    f32x4 acc[4] = {};

    #pragma unroll
    for (int k0 = 0; k0 < C2; k0 += 64) {
        #pragma unroll
        for (int h = 0; h < 2; h++) {
            bf16x8 af, bfr[4];
            af = *(const bf16x8*)&fsm[(wm * 16 + r) * 264 + k0 + h * 32 + q * 8];
            #pragma unroll
            for (int j = 0; j < 4; j++)
                bfr[j] = *(const bf16x8*)(Bt +
                    (size_t)(wn * 64 + j * 16 + r) * C2 + k0 + h * 32 + q * 8);
            #pragma unroll
            for (int j = 0; j < 4; j++)
                acc[j] = __builtin_amdgcn_mfma_f32_16x16x32_bf16(
                    af, bfr[j], acc[j], 0, 0, 0);
        }
    }
    __syncthreads();   // all feat reads done -> safe to alias STF onto fsm

    // epilogue: stage fp32 tile in aliased LDS, then full-line float4 flush
    float* STF = (float*)fsm;              // [32][132]
    #pragma unroll
    for (int j = 0; j < 4; j++) {
        const int ch = wn * 64 + j * 16 + r;
        const float bo = bias[ch];
        const int mb = wm * 16 + q * 4;
        #pragma unroll
        for (int p = 0; p < 4; p++)
            STF[(mb + p) * 132 + ch] = acc[j][p] + bo;
    }
    __syncthreads();
    #pragma unroll
    for (int i = 0; i < 4; i++) {          // 32x128 fp32 = 1024 float4
        int idx = tid + i * 256;
        int row = idx >> 5, c4 = (idx & 31) * 4;
        if (m0 + row < N)
            *(float4*)(Cf + (size_t)(m0 + row) * C_OUT + c4) =
                *(const float4*)&STF[row * 132 + c4];
    }
}

extern "C" void kernel_launch(void* const* d_in, const int* in_sizes, int n_in,
                              void* d_out, int out_size, void* d_ws, size_t ws_size,
                              hipStream_t stream)
{
    const float* features = (const float*)d_in[0];
    const int*   nidx     = (const int*)d_in[1];
    const float* W1       = (const float*)d_in[2];
    const float* b1       = (const float*)d_in[3];
    const float* gamma    = (const float*)d_in[4];
    const float* beta     = (const float*)d_in[5];
    const float* mean     = (const float*)d_in[6];
    const float* var      = (const float*)d_in[7];
    const float* Ws       = (const float*)d_in[8];
    const float* Wm       = (const float*)d_in[9];
    const float* bm       = (const float*)d_in[10];
    float* out = (float*)d_out;

    const int N = in_sizes[0] / C_IN;   // 50000

    u16* packed = (u16*)d_ws;                      // N x 512: [ey 256 | x 256]
    u16* W1t    = packed + (size_t)N * 512;        // 256 x 128 (sigma rows)
    u16* Wst    = W1t + 256 * 128;                 // 256 x 256 (sigma rows)
    u16* Wmt    = Wst + 256 * 256;                 // 128 x 256
    float* bnp  = (float*)(Wmt + 128 * 256);       // 3 x 256 folded BN planes

    prep_k<<<dim3(256, 4), 256, 0, stream>>>(W1, Ws, Wm, b1, gamma, beta,
                                             mean, var, W1t, Wst, Wmt, bnp);

    const int GT = (N + PTS - 1) / PTS;  // 1563

    mlp1_k<<<512, 512, 0, stream>>>(features, W1t, bnp, packed, N);
    mlp2_k<<<256, 512, 0, stream>>>(Wst, packed, N);
    gather_out_k<<<GT, 256, 0, stream>>>(packed, nidx, Wmt, bm, out, N);
}

// Round 12
// 404.405 us; speedup vs baseline: 1.0056x; 1.0056x over previous
//
#include <hip/hip_runtime.h>
#include <cstddef>

// Problem shape (fixed): N=50000, K=16, C_IN=128, C2=256, C_OUT=128.
#define C_IN  128
#define C2    256
#define C_OUT 128
#define KNBR  16
#define PTS   32     // points per gather_out block

typedef unsigned short u16;
typedef __attribute__((ext_vector_type(8))) short bf16x8;   // 8 bf16 (4 VGPRs)
typedef __attribute__((ext_vector_type(4))) float f32x4;

__device__ __forceinline__ float bf2f(u16 h) {
    return __uint_as_float(((unsigned int)h) << 16);
}
__device__ __forceinline__ u16 f2bf(float x) {
    unsigned int u = __float_as_uint(x);
    return (u16)((u + 0x7fffu + ((u >> 16) & 1u)) >> 16);
}

// Channel permutation: weight row rho = 16j+4q+p is STORED at packed position
// sigma(rho) = 32*(j>>1) + 8q + 4*(j&1) + p. Permuting W rows by sigma in prep
// makes the mlp lane's natural burst-store layout equal STANDARD channel order.
__device__ __forceinline__ int sigma_p(int n) {
    return ((n >> 5) << 5) | (((n >> 2) & 3) << 3) | (((n >> 4) & 1) << 2) | (n & 3);
}

// Transpose + convert weights to bf16, n-major [N][K] with sigma-permuted rows
// for W1t/Wst; fold BN params (SoA, standard channel order).
__global__ void prep_k(const float* __restrict__ W1, const float* __restrict__ Ws,
                       const float* __restrict__ Wm, const float* __restrict__ b1,
                       const float* __restrict__ gamma, const float* __restrict__ beta,
                       const float* __restrict__ mean, const float* __restrict__ var,
                       u16* __restrict__ W1t, u16* __restrict__ Wst,
                       u16* __restrict__ Wmt, float* __restrict__ bnp)
{
    const int n = blockIdx.x, t = threadIdx.x;
    if (blockIdx.y == 0) {
        if (t < 128) W1t[n * 128 + t] = f2bf(W1[t * 256 + sigma_p(n)]);
    } else if (blockIdx.y == 1) {
        Wst[n * 256 + t] = f2bf(Ws[t * 256 + sigma_p(n)]);
    } else if (blockIdx.y == 2) {
        if (n < 128) Wmt[n * 256 + t] = f2bf(Wm[t * 128 + n]);
    } else if (n == 0) {
        // x = (relu(z+b1)-mu)*iv + be = relu(z+c1)*c2 + c3, SoA planes
        float iv = gamma[t] * rsqrtf(var[t] + 1e-5f);
        bnp[t]       = b1[t];
        bnp[256 + t] = iv;
        bnp[512 + t] = beta[t] - mean[t] * iv;
    }
}

// ---------------------------------------------------------------------------
// LESSONS ENCODED:
//  R7:  accumulator arrays indexed by non-unrolled loop vars spill to scratch.
//  R12: gather random-read fabric ~3.4 TB/s at full occupancy; FETCH ~370 MB
//       structural. NEVER split the grid below residency (R6: -40 us).
//  R14: launch_bounds cap below per-phase live state => silent scratch spill.
//  R18: OPERAND SWAP: mfma(W_frag, F_frag) puts points in lane&15, channels
//       in (lane>>4)*4+p -> per-point channel-contiguous output chunks.
//  R21: three store-layout fixes left traffic IDENTICAL => excess WRITE
//       (~175MB, drains to HBM) vs smaller excess FETCH (~65MB, reloads hit
//       L2) is the SPILL signature; VGPR pinned at exactly 128 = at-cap.
//  R22 (this round): R11's (512,2) A/B was INVALID: 2 blocks x 8 waves =
//       16 waves/CU => VGPR cap is STILL 128 (pool halves at 64/128/256).
//       Correct lift: (512,1) -> 8 waves/CU -> cap 256. mlp2 is LDS-bound to
//       1 block/CU anyway; mlp1 trades 16->8 waves/CU for no-spill.
// packed row (512 u16): [ey 256 | x 256] halves, standard channel order.
// ---------------------------------------------------------------------------

// mlp1: x = BN(relu(F @ W1 + b1)) -> packed x-half.
// W1t(sigma) in LDS once (69.6 KB). Zero barriers in the loop; 16 points per
// wave-tile; burst 64B-sector stores. (512,1): VGPR cap 256 -> no spill.
__global__ __launch_bounds__(512, 1)
void mlp1_k(const float* __restrict__ F, const u16* __restrict__ W1t,
            const float* __restrict__ bnp, u16* __restrict__ packed, int N)
{
    __shared__ u16 Wl[256 * 136];   // 69.6 KB, stride 136 (2-way banks)
    const int tid = threadIdx.x;
    const int w = tid >> 6, l = tid & 63, q = l >> 4, r = l & 15;

    #pragma unroll
    for (int i = 0; i < 8; i++) {          // 4096 uint4, 8/thread
        int idx = tid + i * 512;
        int row = idx >> 4, g = (idx & 15) * 8;
        *(uint4*)&Wl[row * 136 + g] = *(const uint4*)(W1t + row * 128 + g);
    }
    __syncthreads();   // the only barrier

    const int nwt = (N + 15) >> 4;          // 3125 wave-tiles
    const int nw = gridDim.x * 8;
    for (int wt = blockIdx.x * 8 + w; wt < nwt; wt += nw) {
        const int base = wt * 16;
        const int gr = min(base + r, N - 1);
        // F as B-operand: lane(q,r) holds B[k=q*8+e][n=r] = F[base+r][k]
        bf16x8 fb[4];
        #pragma unroll
        for (int kt = 0; kt < 4; kt++) {
            const float* s = F + (size_t)gr * C_IN + kt * 32 + q * 8;
            float4 v0 = *(const float4*)s;
            float4 v1 = *(const float4*)(s + 4);
            bf16x8 a;
            a[0] = (short)f2bf(v0.x); a[1] = (short)f2bf(v0.y);
            a[2] = (short)f2bf(v0.z); a[3] = (short)f2bf(v0.w);
            a[4] = (short)f2bf(v1.x); a[5] = (short)f2bf(v1.y);
            a[6] = (short)f2bf(v1.z); a[7] = (short)f2bf(v1.w);
            fb[kt] = a;
        }
        const bool ok = (base + r) < N;
        uint2 ob[16];                        // 32 VGPR output buffer
        #pragma unroll
        for (int j = 0; j < 16; j++) {
            f32x4 acc = {0.f, 0.f, 0.f, 0.f};
            #pragma unroll
            for (int kt = 0; kt < 4; kt++) {
                bf16x8 wa = *(const bf16x8*)&Wl[(j * 16 + r) * 136 + kt * 32 + q * 8];
                acc = __builtin_amdgcn_mfma_f32_16x16x32_bf16(wa, fb[kt], acc, 0, 0, 0);
            }
            // standard channel of value p = 32*(j>>1) + 8q + 4*(j&1) + p
            const int c0p = ((j >> 1) << 5) + (q << 3) + ((j & 1) << 2);
            const float4 b1v = *(const float4*)&bnp[c0p];
            const float4 ivv = *(const float4*)&bnp[256 + c0p];
            const float4 bev = *(const float4*)&bnp[512 + c0p];
            u16 h0 = f2bf(fmaxf(acc[0] + b1v.x, 0.f) * ivv.x + bev.x);
            u16 h1 = f2bf(fmaxf(acc[1] + b1v.y, 0.f) * ivv.y + bev.y);
            u16 h2 = f2bf(fmaxf(acc[2] + b1v.z, 0.f) * ivv.z + bev.z);
            u16 h3 = f2bf(fmaxf(acc[3] + b1v.w, 0.f) * ivv.w + bev.w);
            ob[j].x = (unsigned)h0 | ((unsigned)h1 << 16);
            ob[j].y = (unsigned)h2 | ((unsigned)h3 << 16);
        }
        if (ok) {   // burst: 8 x 16B/lane; 4 q-lanes = full 64B sector per row
            u16* rowp = packed + (size_t)(base + r) * 512 + 256 + q * 8;
            #pragma unroll
            for (int s = 0; s < 8; s++) {
                uint4 v;
                v.x = ob[2 * s].x;     v.y = ob[2 * s].y;
                v.z = ob[2 * s + 1].x; v.w = ob[2 * s + 1].y;
                *(uint4*)(rowp + s * 32) = v;
            }
        }
    }
}

// mlp2: ey = exp(x @ Ws) -> packed ey-half. Same structure; Wst(sigma) in LDS
// (132 KB, 1 block/CU of 8 independent waves); x-half read back coalesced.
// (512,1): VGPR cap 256 -> no spill (LDS already limits to 1 block/CU).
__global__ __launch_bounds__(512, 1)
void mlp2_k(const u16* __restrict__ Wst, u16* __restrict__ packed, int N)
{
    __shared__ u16 Wsl[256 * 264];  // 132 KB, stride 264 (2-way banks)
    const int tid = threadIdx.x;
    const int w = tid >> 6, l = tid & 63, q = l >> 4, r = l & 15;

    #pragma unroll
    for (int i = 0; i < 16; i++) {         // 8192 uint4, 16/thread
        int idx = tid + i * 512;
        int row = idx >> 5, g = (idx & 31) * 8;
        *(uint4*)&Wsl[row * 264 + g] = *(const uint4*)(Wst + row * 256 + g);
    }
    __syncthreads();   // the only barrier

    const int nwt = (N + 15) >> 4;          // 3125 wave-tiles
    const int nw = gridDim.x * 8;
    for (int wt = blockIdx.x * 8 + w; wt < nwt; wt += nw) {
        const int base = wt * 16;
        const int gr = min(base + r, N - 1);
        // x as B-operand: lane(q,r) holds B[k=q*8+e][n=r] = x[base+r][k]
        bf16x8 xb[8];
        #pragma unroll
        for (int kt = 0; kt < 8; kt++)
            xb[kt] = *(const bf16x8*)(packed + (size_t)gr * 512 + 256 + kt * 32 + q * 8);
        const bool ok = (base + r) < N;
        uint2 ob[16];
        #pragma unroll
        for (int j = 0; j < 16; j++) {
            f32x4 acc = {0.f, 0.f, 0.f, 0.f};
            #pragma unroll
            for (int kt = 0; kt < 8; kt++) {
                bf16x8 wa = *(const bf16x8*)&Wsl[(j * 16 + r) * 264 + kt * 32 + q * 8];
                acc = __builtin_amdgcn_mfma_f32_16x16x32_bf16(wa, xb[kt], acc, 0, 0, 0);
            }
            u16 h0 = f2bf(__expf(acc[0]));
            u16 h1 = f2bf(__expf(acc[1]));
            u16 h2 = f2bf(__expf(acc[2]));
            u16 h3 = f2bf(__expf(acc[3]));
            ob[j].x = (unsigned)h0 | ((unsigned)h1 << 16);
            ob[j].y = (unsigned)h2 | ((unsigned)h3 << 16);
        }
        if (ok) {
            u16* rowp = packed + (size_t)(base + r) * 512 + q * 8;
            #pragma unroll
            for (int s = 0; s < 8; s++) {
                uint4 v;
                v.x = ob[2 * s].x;     v.y = ob[2 * s].y;
                v.z = ob[2 * s + 1].x; v.w = ob[2 * s + 1].y;
                *(uint4*)(rowp + s * 32) = v;
            }
        }
    }
}

// Fused gather + attentive pool + output GEMM. 32 points/block, 4 waves.
// Phase 1: each wave pools 8 points; 16 rows in TWO passes of 8 neighbors
//          (ey-half + x-half ushort4 loads, 32-VGPR payload -> no scratch).
// Phase 2: out[32 x 128] = feat @ Wmt + bm, B direct from L2-resident Wmt;
//          fp32 epilogue staging ALIASES the feat buffer.
// Single 1563-block dispatch (R12: never split below residency capacity).
__global__ __launch_bounds__(256, 5)
void gather_out_k(const u16* __restrict__ packed, const int* __restrict__ nidx,
                  const u16* __restrict__ Bt, const float* __restrict__ bias,
                  float* __restrict__ Cf, int N)
{
    __shared__ int rows[PTS * KNBR];                 // 2 KB
    __shared__ __align__(16) u16 fsm[PTS * 264];     // feat bf16 / STF fp32 alias

    const int tid = threadIdx.x;
    const int w = tid >> 6, l = tid & 63, q = l >> 4, r = l & 15;
    const int m0 = blockIdx.x * PTS;

    // stage neighbor indices: PTS*16 = 512 ints, 2/thread
    #pragma unroll
    for (int i = 0; i < 2; i++) {
        int idx = tid + i * 256;
        int n = m0 + (idx >> 4);
        rows[idx] = (n < N) ? nidx[n * KNBR + (idx & 15)] : 0;
    }
    __syncthreads();

    // ---- phase 1: gather + pool, wave w -> points w*8 .. w*8+7 ----
    #pragma unroll 1
    for (int ip = 0; ip < 8; ip++) {
        const int pl = w * 8 + ip;
        float num[4] = {0.f, 0.f, 0.f, 0.f};
        float den[4] = {0.f, 0.f, 0.f, 0.f};
        #pragma unroll 1
        for (int hf = 0; hf < 2; hf++) {
            ushort4 eh[8], xh[8];
            #pragma unroll
            for (int k = 0; k < 8; k++) {
                const size_t b = (size_t)rows[pl * KNBR + hf * 8 + k] * 512;
                eh[k] = *(const ushort4*)(packed + b + l * 4);
                xh[k] = *(const ushort4*)(packed + b + 256 + l * 4);
            }
            #pragma unroll
            for (int k = 0; k < 8; k++) {
                float e0 = bf2f(eh[k].x), e1 = bf2f(eh[k].y);
                float e2 = bf2f(eh[k].z), e3 = bf2f(eh[k].w);
                den[0] += e0; den[1] += e1; den[2] += e2; den[3] += e3;
                num[0] = fmaf(e0, bf2f(xh[k].x), num[0]);
                num[1] = fmaf(e1, bf2f(xh[k].y), num[1]);
                num[2] = fmaf(e2, bf2f(xh[k].z), num[2]);
                num[3] = fmaf(e3, bf2f(xh[k].w), num[3]);
            }
        }
        ushort4 o;
        o.x = f2bf(num[0] / den[0]); o.y = f2bf(num[1] / den[1]);
        o.z = f2bf(num[2] / den[2]); o.w = f2bf(num[3] / den[3]);
        *(ushort4*)&fsm[pl * 264 + l * 4] = o;   // rows >= N: garbage, never stored
    }
    __syncthreads();   // feat tile complete

    // ---- phase 2: out GEMM, wave grid 2M x 2N; B direct from L2 ----
    const int wm = w & 1, wn = w >> 1;
    f32x4 acc[4] = {};

    #pragma unroll
    for (int k0 = 0; k0 < C2; k0 += 64) {
        #pragma unroll
        for (int h = 0; h < 2; h++) {
            bf16x8 af, bfr[4];
            af = *(const bf16x8*)&fsm[(wm * 16 + r) * 264 + k0 + h * 32 + q * 8];
            #pragma unroll
            for (int j = 0; j < 4; j++)
                bfr[j] = *(const bf16x8*)(Bt +
                    (size_t)(wn * 64 + j * 16 + r) * C2 + k0 + h * 32 + q * 8);
            #pragma unroll
            for (int j = 0; j < 4; j++)
                acc[j] = __builtin_amdgcn_mfma_f32_16x16x32_bf16(
                    af, bfr[j], acc[j], 0, 0, 0);
        }
    }
    __syncthreads();   // all feat reads done -> safe to alias STF onto fsm

    // epilogue: stage fp32 tile in aliased LDS, then full-line float4 flush
    float* STF = (float*)fsm;              // [32][132]
    #pragma unroll
    for (int j = 0; j < 4; j++) {
        const int ch = wn * 64 + j * 16 + r;
        const float bo = bias[ch];
        const int mb = wm * 16 + q * 4;
        #pragma unroll
        for (int p = 0; p < 4; p++)
            STF[(mb + p) * 132 + ch] = acc[j][p] + bo;
    }
    __syncthreads();
    #pragma unroll
    for (int i = 0; i < 4; i++) {          // 32x128 fp32 = 1024 float4
        int idx = tid + i * 256;
        int row = idx >> 5, c4 = (idx & 31) * 4;
        if (m0 + row < N)
            *(float4*)(Cf + (size_t)(m0 + row) * C_OUT + c4) =
                *(const float4*)&STF[row * 132 + c4];
    }
}

extern "C" void kernel_launch(void* const* d_in, const int* in_sizes, int n_in,
                              void* d_out, int out_size, void* d_ws, size_t ws_size,
                              hipStream_t stream)
{
    const float* features = (const float*)d_in[0];
    const int*   nidx     = (const int*)d_in[1];
    const float* W1       = (const float*)d_in[2];
    const float* b1       = (const float*)d_in[3];
    const float* gamma    = (const float*)d_in[4];
    const float* beta     = (const float*)d_in[5];
    const float* mean     = (const float*)d_in[6];
    const float* var      = (const float*)d_in[7];
    const float* Ws       = (const float*)d_in[8];
    const float* Wm       = (const float*)d_in[9];
    const float* bm       = (const float*)d_in[10];
    float* out = (float*)d_out;

    const int N = in_sizes[0] / C_IN;   // 50000

    u16* packed = (u16*)d_ws;                      // N x 512: [ey 256 | x 256]
    u16* W1t    = packed + (size_t)N * 512;        // 256 x 128 (sigma rows)
    u16* Wst    = W1t + 256 * 128;                 // 256 x 256 (sigma rows)
    u16* Wmt    = Wst + 256 * 256;                 // 128 x 256
    float* bnp  = (float*)(Wmt + 128 * 256);       // 3 x 256 folded BN planes

    prep_k<<<dim3(256, 4), 256, 0, stream>>>(W1, Ws, Wm, b1, gamma, beta,
                                             mean, var, W1t, Wst, Wmt, bnp);

    const int GT = (N + PTS - 1) / PTS;  // 1563

    mlp1_k<<<512, 512, 0, stream>>>(features, W1t, bnp, packed, N);
    mlp2_k<<<256, 512, 0, stream>>>(Wst, packed, N);
    gather_out_k<<<GT, 256, 0, stream>>>(packed, nidx, Wmt, bm, out, N);
}

// Round 13
// 259.638 us; speedup vs baseline: 1.5662x; 1.5576x over previous
//
#include <hip/hip_runtime.h>
#include <cstddef>

// Problem shape (fixed): N=50000, K=16, C_IN=128, C2=256, C_OUT=128.
#define C_IN  128
#define C2    256
#define C_OUT 128
#define KNBR  16
#define PTS   32     // points per gather_out block

typedef unsigned short u16;
typedef __attribute__((ext_vector_type(8))) short bf16x8;   // 8 bf16 (4 VGPRs)
typedef __attribute__((ext_vector_type(8))) unsigned short u16x8; // 16B payload
typedef __attribute__((ext_vector_type(4))) float f32x4;

__device__ __forceinline__ float bf2f(u16 h) {
    return __uint_as_float(((unsigned int)h) << 16);
}
__device__ __forceinline__ u16 f2bf(float x) {
    unsigned int u = __float_as_uint(x);
    return (u16)((u + 0x7fffu + ((u >> 16) & 1u)) >> 16);
}

// Transpose + convert weights to bf16, n-major [N][K]; fold BN params.
__global__ void prep_k(const float* __restrict__ W1, const float* __restrict__ Ws,
                       const float* __restrict__ Wm, const float* __restrict__ b1,
                       const float* __restrict__ gamma, const float* __restrict__ beta,
                       const float* __restrict__ mean, const float* __restrict__ var,
                       u16* __restrict__ W1t, u16* __restrict__ Wst,
                       u16* __restrict__ Wmt, float4* __restrict__ bnp)
{
    const int n = blockIdx.x, t = threadIdx.x;
    if (blockIdx.y == 0) {
        if (t < 128) W1t[n * 128 + t] = f2bf(W1[t * 256 + n]);
    } else if (blockIdx.y == 1) {
        Wst[n * 256 + t] = f2bf(Ws[t * 256 + n]);
    } else if (blockIdx.y == 2) {
        if (n < 128) Wmt[n * 256 + t] = f2bf(Wm[t * 128 + n]);
    } else if (n == 0) {
        // x = (relu(z+b1)-mu)*iv + be = relu(z+c1)*c2 + c3
        float iv = gamma[t] * rsqrtf(var[t] + 1e-5f);
        bnp[t] = make_float4(b1[t], iv, beta[t] - mean[t] * iv, 0.f);
    }
}

// ---------------------------------------------------------------------------
// LESSONS ENCODED (final ledger):
//  R7:  accumulator arrays indexed by non-unrolled loop vars spill to scratch.
//  R12: gather random-read fabric ~3.4 TB/s at full occupancy; FETCH ~370 MB
//       structural. NEVER split the grid below residency (R6: -40 us).
//  R14: launch_bounds cap below per-phase live state => silent scratch spill.
//  R15: GEMM2's ey(row,col) lane == GEMM1's x(row,col) lane -> keep x in
//       VGPRs, store (ey|x<<16) dword lane-locally. No ey LDS staging.
//  R23 (this round): the weight-stationary grid-stride mlp carries an
//       unexplained ~8x WRITE inflation (201 MB for 25.6 logical) that
//       survived FOUR theories (RMW width, sector scatter, spill, cap
//       arithmetic) - VGPR=128 natural, no spill. ABANDON that structure.
//       Compose measured components instead: R6's barrier-tiled mlp_k
//       (bounded 87-94 us by R6's top-5 exclusion) + R4/R5's single-dispatch
//       gather_out_k (121 us, stable over 3 rounds).
// packed row (512 u16): 256 pairs of (ey[c], x[c]), both bf16 (interleaved).
// ---------------------------------------------------------------------------

// Fused MLP, 64-row blocks (52.2 KB LDS -> 3 blocks/CU), 4 waves (2M x 2N):
//   GEMM1: x = BN(relu(F @ W1 + b1)) -> xs (LDS, for GEMM2-A) + xr (VGPR)
//   GEMM2: ey = exp(x @ Ws) -> lane-local interleaved (ey|x) dword stores
// [R6-measured: <= 94 us; passed correctness in R6's bench]
__global__ __launch_bounds__(256, 3)
void mlp_k(const float* __restrict__ F, const u16* __restrict__ W1t,
           const u16* __restrict__ Wst, const float4* __restrict__ bnp,
           u16* __restrict__ packed, int N)
{
    __shared__ u16 Bs[128][72];    // weight k-slice staging   (18.4 KB)
    __shared__ u16 xs[64][264];    // x tile, full K=256       (33.8 KB)

    const int tid = threadIdx.x;
    const int w = tid >> 6, l = tid & 63, q = l >> 4, r = l & 15;
    const int wm = w & 1, wn = w >> 1;
    const int m0 = blockIdx.x * 64;

    // ---- A-fragments direct from F into regs (no As tile): af1[i][kt] ----
    bf16x8 af1[2][4];
    #pragma unroll
    for (int i = 0; i < 2; i++) {
        const int gr = m0 + wm * 32 + i * 16 + r;
        #pragma unroll
        for (int t = 0; t < 4; t++) {
            float4 v0 = make_float4(0.f, 0.f, 0.f, 0.f), v1 = v0;
            if (gr < N) {
                const float* s = F + (size_t)gr * C_IN + t * 32 + q * 8;
                v0 = *(const float4*)s;
                v1 = *(const float4*)(s + 4);
            }
            bf16x8 a;
            a[0] = (short)f2bf(v0.x); a[1] = (short)f2bf(v0.y);
            a[2] = (short)f2bf(v0.z); a[3] = (short)f2bf(v0.w);
            a[4] = (short)f2bf(v1.x); a[5] = (short)f2bf(v1.y);
            a[6] = (short)f2bf(v1.z); a[7] = (short)f2bf(v1.w);
            af1[i][t] = a;
        }
    }

    // x kept in registers, bf16-packed: [nh][i][j] ushort4
    ushort4 xr[2][2][4];

    // ---- GEMM1: x = F @ W1, two 128-col halves (A from regs) ----
    #pragma unroll
    for (int nh = 0; nh < 2; nh++) {
        f32x4 acc[2][4] = {};
        #pragma unroll 1
        for (int k0 = 0; k0 < C_IN; k0 += 64) {
            __syncthreads();   // prior Bs readers done
            #pragma unroll
            for (int i = 0; i < 4; i++) {
                int idx = tid + i * 256;
                int row = idx >> 3, g = (idx & 7) * 8;
                *(uint4*)&Bs[row][g] = *(const uint4*)(
                    W1t + (size_t)(nh * 128 + row) * C_IN + k0 + g);
            }
            __syncthreads();
            #pragma unroll
            for (int h = 0; h < 2; h++) {
                const int kt = (k0 >> 5) + h;
                bf16x8 bfr[4];
                #pragma unroll
                for (int j = 0; j < 4; j++)
                    bfr[j] = *(const bf16x8*)&Bs[wn * 64 + j * 16 + r][h * 32 + q * 8];
                #pragma unroll
                for (int i = 0; i < 2; i++)
                    #pragma unroll
                    for (int j = 0; j < 4; j++)
                        acc[i][j] = __builtin_amdgcn_mfma_f32_16x16x32_bf16(
                            af1[i][kt], bfr[j], acc[i][j], 0, 0, 0);
            }
        }
        // epilogue 1: x = relu(z+c1)*c2+c3 -> xs (LDS) AND xr (VGPR, bf16)
        #pragma unroll
        for (int j = 0; j < 4; j++) {
            const int ch = nh * 128 + wn * 64 + j * 16 + r;
            const float4 bp = bnp[ch];
            #pragma unroll
            for (int i = 0; i < 2; i++) {
                const int mb = wm * 32 + i * 16 + q * 4;
                ushort4 hx;
                #pragma unroll
                for (int p = 0; p < 4; p++) {
                    float x = fmaxf(acc[i][j][p] + bp.x, 0.f) * bp.y + bp.z;
                    u16 h = f2bf(x);
                    xs[mb + p][ch] = h;
                    if (p == 0) hx.x = h; else if (p == 1) hx.y = h;
                    else if (p == 2) hx.z = h; else hx.w = h;
                }
                xr[nh][i][j] = hx;
            }
        }
    }

    // ---- GEMM2: ey = exp(x @ Ws); A from xs; direct lane-local epilogue ----
    #pragma unroll
    for (int nh = 0; nh < 2; nh++) {
        f32x4 acc[2][4] = {};
        #pragma unroll 1
        for (int k0 = 0; k0 < C2; k0 += 64) {
            __syncthreads();   // prior Bs readers done; 1st iter: xs complete
            #pragma unroll
            for (int i = 0; i < 4; i++) {
                int idx = tid + i * 256;
                int row = idx >> 3, g = (idx & 7) * 8;
                *(uint4*)&Bs[row][g] = *(const uint4*)(
                    Wst + (size_t)(nh * 128 + row) * C2 + k0 + g);
            }
            __syncthreads();
            #pragma unroll
            for (int h = 0; h < 2; h++) {
                bf16x8 af[2], bfr[4];
                #pragma unroll
                for (int i = 0; i < 2; i++)
                    af[i] = *(const bf16x8*)&xs[wm * 32 + i * 16 + r][k0 + h * 32 + q * 8];
                #pragma unroll
                for (int j = 0; j < 4; j++)
                    bfr[j] = *(const bf16x8*)&Bs[wn * 64 + j * 16 + r][h * 32 + q * 8];
                #pragma unroll
                for (int i = 0; i < 2; i++)
                    #pragma unroll
                    for (int j = 0; j < 4; j++)
                        acc[i][j] = __builtin_amdgcn_mfma_f32_16x16x32_bf16(
                            af[i], bfr[j], acc[i][j], 0, 0, 0);
            }
        }
        // epilogue 2: ey=exp(acc); pair with register-held x (layout identity)
        #pragma unroll
        for (int j = 0; j < 4; j++) {
            const int ch = nh * 128 + wn * 64 + j * 16 + r;
            #pragma unroll
            for (int i = 0; i < 2; i++) {
                const int mb = wm * 32 + i * 16 + q * 4;
                const ushort4 hx = xr[nh][i][j];
                #pragma unroll
                for (int p = 0; p < 4; p++) {
                    const int gm = m0 + mb + p;
                    if (gm < N) {
                        unsigned xv = (p == 0) ? hx.x : (p == 1) ? hx.y
                                    : (p == 2) ? hx.z : hx.w;
                        unsigned ey = f2bf(__expf(acc[i][j][p]));
                        *(unsigned*)(packed + (size_t)gm * 512 + ch * 2) =
                            ey | (xv << 16);
                    }
                }
            }
        }
    }
}

// Fused gather + attentive pool + output GEMM. 32 points/block, 4 waves.
// Phase 1: each wave pools 8 points; 16 rows gathered in TWO passes of 8
//          (32-VGPR payload, fits under the (256,5) cap -> no scratch).
// Phase 2: out[32 x 128] = feat @ Wmt + bm, B direct from L2-resident Wmt;
//          fp32 epilogue staging ALIASES the feat buffer.
// Single 1563-block dispatch (R12). [R4/R5-measured: ~121 us]
__global__ __launch_bounds__(256, 5)
void gather_out_k(const u16* __restrict__ packed, const int* __restrict__ nidx,
                  const u16* __restrict__ Bt, const float* __restrict__ bias,
                  float* __restrict__ Cf, int N)
{
    __shared__ int rows[PTS * KNBR];                 // 2 KB
    __shared__ __align__(16) u16 fsm[PTS * 264];     // feat bf16 / STF fp32 alias

    const int tid = threadIdx.x;
    const int w = tid >> 6, l = tid & 63, q = l >> 4, r = l & 15;
    const int m0 = blockIdx.x * PTS;

    // stage neighbor indices: PTS*16 = 512 ints, 2/thread
    #pragma unroll
    for (int i = 0; i < 2; i++) {
        int idx = tid + i * 256;
        int n = m0 + (idx >> 4);
        rows[idx] = (n < N) ? nidx[n * KNBR + (idx & 15)] : 0;
    }
    __syncthreads();

    // ---- phase 1: gather + pool, wave w -> points w*8 .. w*8+7 ----
    #pragma unroll 1
    for (int ip = 0; ip < 8; ip++) {
        const int pl = w * 8 + ip;
        float num[4] = {0.f, 0.f, 0.f, 0.f};
        float den[4] = {0.f, 0.f, 0.f, 0.f};
        #pragma unroll 1
        for (int hf = 0; hf < 2; hf++) {
            u16x8 v[8];
            #pragma unroll
            for (int k = 0; k < 8; k++)
                v[k] = *(const u16x8*)(packed +
                    (size_t)rows[pl * KNBR + hf * 8 + k] * 512 + l * 8);
            #pragma unroll
            for (int k = 0; k < 8; k++) {
                #pragma unroll
                for (int c = 0; c < 4; c++) {
                    float e = bf2f((u16)v[k][2 * c]);
                    float x = bf2f((u16)v[k][2 * c + 1]);
                    den[c] += e;
                    num[c] = fmaf(e, x, num[c]);
                }
            }
        }
        ushort4 o;
        o.x = f2bf(num[0] / den[0]); o.y = f2bf(num[1] / den[1]);
        o.z = f2bf(num[2] / den[2]); o.w = f2bf(num[3] / den[3]);
        *(ushort4*)&fsm[pl * 264 + l * 4] = o;   // rows >= N: garbage, never stored
    }
    __syncthreads();   // feat tile complete

    // ---- phase 2: out GEMM, wave grid 2M x 2N; B direct from L2 ----
    const int wm = w & 1, wn = w >> 1;
    f32x4 acc[4] = {};

    #pragma unroll
    for (int k0 = 0; k0 < C2; k0 += 64) {
        #pragma unroll
        for (int h = 0; h < 2; h++) {
            bf16x8 af, bfr[4];
            af = *(const bf16x8*)&fsm[(wm * 16 + r) * 264 + k0 + h * 32 + q * 8];
            #pragma unroll
            for (int j = 0; j < 4; j++)
                bfr[j] = *(const bf16x8*)(Bt +
                    (size_t)(wn * 64 + j * 16 + r) * C2 + k0 + h * 32 + q * 8);
            #pragma unroll
            for (int j = 0; j < 4; j++)
                acc[j] = __builtin_amdgcn_mfma_f32_16x16x32_bf16(
                    af, bfr[j], acc[j], 0, 0, 0);
        }
    }
    __syncthreads();   // all feat reads done -> safe to alias STF onto fsm

    // epilogue: stage fp32 tile in aliased LDS, then full-line float4 flush
    float* STF = (float*)fsm;              // [32][132]
    #pragma unroll
    for (int j = 0; j < 4; j++) {
        const int ch = wn * 64 + j * 16 + r;
        const float bo = bias[ch];
        const int mb = wm * 16 + q * 4;
        #pragma unroll
        for (int p = 0; p < 4; p++)
            STF[(mb + p) * 132 + ch] = acc[j][p] + bo;
    }
    __syncthreads();
    #pragma unroll
    for (int i = 0; i < 4; i++) {          // 32x128 fp32 = 1024 float4
        int idx = tid + i * 256;
        int row = idx >> 5, c4 = (idx & 31) * 4;
        if (m0 + row < N)
            *(float4*)(Cf + (size_t)(m0 + row) * C_OUT + c4) =
                *(const float4*)&STF[row * 132 + c4];
    }
}

extern "C" void kernel_launch(void* const* d_in, const int* in_sizes, int n_in,
                              void* d_out, int out_size, void* d_ws, size_t ws_size,
                              hipStream_t stream)
{
    const float* features = (const float*)d_in[0];
    const int*   nidx     = (const int*)d_in[1];
    const float* W1       = (const float*)d_in[2];
    const float* b1       = (const float*)d_in[3];
    const float* gamma    = (const float*)d_in[4];
    const float* beta     = (const float*)d_in[5];
    const float* mean     = (const float*)d_in[6];
    const float* var      = (const float*)d_in[7];
    const float* Ws       = (const float*)d_in[8];
    const float* Wm       = (const float*)d_in[9];
    const float* bm       = (const float*)d_in[10];
    float* out = (float*)d_out;

    const int N = in_sizes[0] / C_IN;   // 50000

    u16* packed = (u16*)d_ws;                      // N x 512 interleaved pairs
    u16* W1t    = packed + (size_t)N * 512;        // 256 x 128
    u16* Wst    = W1t + 256 * 128;                 // 256 x 256
    u16* Wmt    = Wst + 256 * 256;                 // 128 x 256
    float4* bnp = (float4*)(Wmt + 128 * 256);      // 256 folded BN params

    prep_k<<<dim3(256, 4), 256, 0, stream>>>(W1, Ws, Wm, b1, gamma, beta,
                                             mean, var, W1t, Wst, Wmt, bnp);

    const int MT = (N + 63) / 64;        // 782
    const int GT = (N + PTS - 1) / PTS;  // 1563

    mlp_k<<<MT, 256, 0, stream>>>(features, W1t, Wst, bnp, packed, N);
    gather_out_k<<<GT, 256, 0, stream>>>(packed, nidx, Wmt, bm, out, N);
}

// Round 14
// 246.423 us; speedup vs baseline: 1.6502x; 1.0536x over previous
//
#include <hip/hip_runtime.h>
#include <cstddef>

// Problem shape (fixed): N=50000, K=16, C_IN=128, C2=256, C_OUT=128.
#define C_IN  128
#define C2    256
#define C_OUT 128
#define KNBR  16
#define PTS   32     // points per gather_out block

typedef unsigned short u16;
typedef __attribute__((ext_vector_type(8))) short bf16x8;   // 8 bf16 (4 VGPRs)
typedef __attribute__((ext_vector_type(8))) unsigned short u16x8; // 16B payload
typedef __attribute__((ext_vector_type(4))) float f32x4;

__device__ __forceinline__ float bf2f(u16 h) {
    return __uint_as_float(((unsigned int)h) << 16);
}
__device__ __forceinline__ u16 f2bf(float x) {
    unsigned int u = __float_as_uint(x);
    return (u16)((u + 0x7fffu + ((u >> 16) & 1u)) >> 16);
}

// Transpose + convert weights to bf16, n-major [N][K]; fold BN params.
__global__ void prep_k(const float* __restrict__ W1, const float* __restrict__ Ws,
                       const float* __restrict__ Wm, const float* __restrict__ b1,
                       const float* __restrict__ gamma, const float* __restrict__ beta,
                       const float* __restrict__ mean, const float* __restrict__ var,
                       u16* __restrict__ W1t, u16* __restrict__ Wst,
                       u16* __restrict__ Wmt, float4* __restrict__ bnp)
{
    const int n = blockIdx.x, t = threadIdx.x;
    if (blockIdx.y == 0) {
        if (t < 128) W1t[n * 128 + t] = f2bf(W1[t * 256 + n]);
    } else if (blockIdx.y == 1) {
        Wst[n * 256 + t] = f2bf(Ws[t * 256 + n]);
    } else if (blockIdx.y == 2) {
        if (n < 128) Wmt[n * 256 + t] = f2bf(Wm[t * 128 + n]);
    } else if (n == 0) {
        // x = (relu(z+b1)-mu)*iv + be = relu(z+c1)*c2 + c3
        float iv = gamma[t] * rsqrtf(var[t] + 1e-5f);
        bnp[t] = make_float4(b1[t], iv, beta[t] - mean[t] * iv, 0.f);
    }
}

// ---------------------------------------------------------------------------
// LESSONS ENCODED (final ledger):
//  R7:  accumulator arrays indexed by non-unrolled loop vars spill to scratch.
//  R12: gather random-read fabric ~3.4 TB/s at full occupancy; FETCH ~370 MB
//       structural (3 load structures identical). NEVER split the grid below
//       residency (R6: -40 us).
//  R14: launch_bounds cap below per-phase live state => silent scratch spill.
//  R15: GEMM2's ey(row,col) lane == GEMM1's x(row,col) lane -> keep x in
//       VGPRs, store (ey|x<<16) dword lane-locally. No ey LDS staging.
//  R23: weight-stationary grid-stride mlp carries an unexplained ~8x WRITE
//       inflation that survived four theories. Abandoned.
//  R24 (this round): cross-bench subtraction with different dispatch counts
//       is NOT a measurement (~40 us constant bench overhead unattributed in
//       per-dispatch profiles made R6's mlp look 25 us faster than it was).
//       Same-context delta: R13's A-direct mlp was +17 us vs R5's As-staged
//       mlp. REVERT to the measured champion (R5 = 241.5 us) exactly.
// packed row (512 u16): 256 pairs of (ey[c], x[c]), both bf16 (interleaved).
// ---------------------------------------------------------------------------

// Fused MLP, 64-row blocks (69.6 KB LDS -> 2 blocks/CU), 4 waves (2M x 2N):
//   GEMM1: x = BN(relu(F @ W1 + b1)) -> xs (LDS, for GEMM2-A) + xr (VGPR)
//   GEMM2: ey = exp(x @ Ws) -> lane-local interleaved (ey|x) dword stores
__global__ __launch_bounds__(256)
void mlp_k(const float* __restrict__ F, const u16* __restrict__ W1t,
           const u16* __restrict__ Wst, const float4* __restrict__ bnp,
           u16* __restrict__ packed, int N)
{
    __shared__ u16 As[64][136];    // features tile (GEMM1 A)
    __shared__ u16 Bs[128][72];    // weight k-slice staging
    __shared__ u16 xs[64][264];    // x tile, full K=256 (GEMM2 A source)

    const int tid = threadIdx.x;
    const int w = tid >> 6, l = tid & 63, q = l >> 4, r = l & 15;
    const int wm = w & 1, wn = w >> 1;
    const int m0 = blockIdx.x * 64;

    // stage As: 64 x 128 fp32 -> bf16 (2048 float4, 8/thread)
    #pragma unroll
    for (int i = 0; i < 8; i++) {
        int idx = tid + i * 256;
        int row = idx >> 5, c4 = (idx & 31) * 4;
        int gm = m0 + row;
        float4 v = make_float4(0.f, 0.f, 0.f, 0.f);
        if (gm < N) v = *(const float4*)(F + (size_t)gm * C_IN + c4);
        ushort4 h;
        h.x = f2bf(v.x); h.y = f2bf(v.y); h.z = f2bf(v.z); h.w = f2bf(v.w);
        *(ushort4*)&As[row][c4] = h;
    }

    // x kept in registers, bf16-packed: [nh][i][j] ushort4
    ushort4 xr[2][2][4];

    // ---- GEMM1: x = F @ W1, two 128-col halves (nh fully unrolled) ----
    #pragma unroll
    for (int nh = 0; nh < 2; nh++) {
        f32x4 acc[2][4] = {};
        #pragma unroll 1
        for (int k0 = 0; k0 < C_IN; k0 += 64) {
            __syncthreads();   // prior Bs readers done (also covers As stage)
            #pragma unroll
            for (int i = 0; i < 4; i++) {
                int idx = tid + i * 256;
                int row = idx >> 3, g = (idx & 7) * 8;
                *(uint4*)&Bs[row][g] = *(const uint4*)(
                    W1t + (size_t)(nh * 128 + row) * C_IN + k0 + g);
            }
            __syncthreads();
            #pragma unroll
            for (int h = 0; h < 2; h++) {
                bf16x8 af[2], bfr[4];
                #pragma unroll
                for (int i = 0; i < 2; i++)
                    af[i] = *(const bf16x8*)&As[wm * 32 + i * 16 + r][k0 + h * 32 + q * 8];
                #pragma unroll
                for (int j = 0; j < 4; j++)
                    bfr[j] = *(const bf16x8*)&Bs[wn * 64 + j * 16 + r][h * 32 + q * 8];
                #pragma unroll
                for (int i = 0; i < 2; i++)
                    #pragma unroll
                    for (int j = 0; j < 4; j++)
                        acc[i][j] = __builtin_amdgcn_mfma_f32_16x16x32_bf16(
                            af[i], bfr[j], acc[i][j], 0, 0, 0);
            }
        }
        // epilogue 1: x = relu(z+c1)*c2+c3 -> xs (LDS) AND xr (VGPR, bf16)
        #pragma unroll
        for (int j = 0; j < 4; j++) {
            const int ch = nh * 128 + wn * 64 + j * 16 + r;
            const float4 bp = bnp[ch];
            #pragma unroll
            for (int i = 0; i < 2; i++) {
                const int mb = wm * 32 + i * 16 + q * 4;
                ushort4 hx;
                #pragma unroll
                for (int p = 0; p < 4; p++) {
                    float x = fmaxf(acc[i][j][p] + bp.x, 0.f) * bp.y + bp.z;
                    u16 h = f2bf(x);
                    xs[mb + p][ch] = h;
                    if (p == 0) hx.x = h; else if (p == 1) hx.y = h;
                    else if (p == 2) hx.z = h; else hx.w = h;
                }
                xr[nh][i][j] = hx;
            }
        }
    }

    // ---- GEMM2: ey = exp(x @ Ws); A from xs; direct lane-local epilogue ----
    #pragma unroll
    for (int nh = 0; nh < 2; nh++) {
        f32x4 acc[2][4] = {};
        #pragma unroll 1
        for (int k0 = 0; k0 < C2; k0 += 64) {
            __syncthreads();   // prior Bs readers done; 1st iter: xs complete
            #pragma unroll
            for (int i = 0; i < 4; i++) {
                int idx = tid + i * 256;
                int row = idx >> 3, g = (idx & 7) * 8;
                *(uint4*)&Bs[row][g] = *(const uint4*)(
                    Wst + (size_t)(nh * 128 + row) * C2 + k0 + g);
            }
            __syncthreads();
            #pragma unroll
            for (int h = 0; h < 2; h++) {
                bf16x8 af[2], bfr[4];
                #pragma unroll
                for (int i = 0; i < 2; i++)
                    af[i] = *(const bf16x8*)&xs[wm * 32 + i * 16 + r][k0 + h * 32 + q * 8];
                #pragma unroll
                for (int j = 0; j < 4; j++)
                    bfr[j] = *(const bf16x8*)&Bs[wn * 64 + j * 16 + r][h * 32 + q * 8];
                #pragma unroll
                for (int i = 0; i < 2; i++)
                    #pragma unroll
                    for (int j = 0; j < 4; j++)
                        acc[i][j] = __builtin_amdgcn_mfma_f32_16x16x32_bf16(
                            af[i], bfr[j], acc[i][j], 0, 0, 0);
            }
        }
        // epilogue 2: ey=exp(acc); pair with register-held x (same lane,
        // same (row,ch) by layout identity); u32 store: 16 consecutive u32
        // per (q-row) -> 4 x 64B segments per instruction. No LDS, no barrier.
        #pragma unroll
        for (int j = 0; j < 4; j++) {
            const int ch = nh * 128 + wn * 64 + j * 16 + r;
            #pragma unroll
            for (int i = 0; i < 2; i++) {
                const int mb = wm * 32 + i * 16 + q * 4;
                const ushort4 hx = xr[nh][i][j];
                #pragma unroll
                for (int p = 0; p < 4; p++) {
                    const int gm = m0 + mb + p;
                    if (gm < N) {
                        unsigned xv = (p == 0) ? hx.x : (p == 1) ? hx.y
                                    : (p == 2) ? hx.z : hx.w;
                        unsigned ey = f2bf(__expf(acc[i][j][p]));
                        *(unsigned*)(packed + (size_t)gm * 512 + ch * 2) =
                            ey | (xv << 16);
                    }
                }
            }
        }
    }
}

// Fused gather + attentive pool + output GEMM. 32 points/block, 4 waves.
// Phase 1: each wave pools 8 points; 16 rows gathered in TWO passes of 8
//          (32-VGPR payload, fits under the (256,5) cap -> no scratch).
// Phase 2: out[32 x 128] = feat @ Wmt + bm, B direct from L2-resident Wmt;
//          fp32 epilogue staging ALIASES the feat buffer.
// LDS: 2KB rows + 16.9KB feat/STF = 18.9KB; VGPR cap 102 -> 5 blocks/CU.
__global__ __launch_bounds__(256, 5)
void gather_out_k(const u16* __restrict__ packed, const int* __restrict__ nidx,
                  const u16* __restrict__ Bt, const float* __restrict__ bias,
                  float* __restrict__ Cf, int N)
{
    __shared__ int rows[PTS * KNBR];                 // 2 KB
    __shared__ __align__(16) u16 fsm[PTS * 264];     // feat bf16 / STF fp32 alias

    const int tid = threadIdx.x;
    const int w = tid >> 6, l = tid & 63, q = l >> 4, r = l & 15;
    const int m0 = blockIdx.x * PTS;

    // stage neighbor indices: PTS*16 = 512 ints, 2/thread
    #pragma unroll
    for (int i = 0; i < 2; i++) {
        int idx = tid + i * 256;
        int n = m0 + (idx >> 4);
        rows[idx] = (n < N) ? nidx[n * KNBR + (idx & 15)] : 0;
    }
    __syncthreads();

    // ---- phase 1: gather + pool, wave w -> points w*8 .. w*8+7 ----
    #pragma unroll 1
    for (int ip = 0; ip < 8; ip++) {
        const int pl = w * 8 + ip;
        float num[4] = {0.f, 0.f, 0.f, 0.f};
        float den[4] = {0.f, 0.f, 0.f, 0.f};
        #pragma unroll 1
        for (int hf = 0; hf < 2; hf++) {
            u16x8 v[8];
            #pragma unroll
            for (int k = 0; k < 8; k++)
                v[k] = *(const u16x8*)(packed +
                    (size_t)rows[pl * KNBR + hf * 8 + k] * 512 + l * 8);
            #pragma unroll
            for (int k = 0; k < 8; k++) {
                #pragma unroll
                for (int c = 0; c < 4; c++) {
                    float e = bf2f((u16)v[k][2 * c]);
                    float x = bf2f((u16)v[k][2 * c + 1]);
                    den[c] += e;
                    num[c] = fmaf(e, x, num[c]);
                }
            }
        }
        ushort4 o;
        o.x = f2bf(num[0] / den[0]); o.y = f2bf(num[1] / den[1]);
        o.z = f2bf(num[2] / den[2]); o.w = f2bf(num[3] / den[3]);
        *(ushort4*)&fsm[pl * 264 + l * 4] = o;   // rows >= N: garbage, never stored
    }
    __syncthreads();   // feat tile complete

    // ---- phase 2: out GEMM, wave grid 2M x 2N; B direct from L2 ----
    const int wm = w & 1, wn = w >> 1;
    f32x4 acc[4] = {};

    #pragma unroll
    for (int k0 = 0; k0 < C2; k0 += 64) {
        #pragma unroll
        for (int h = 0; h < 2; h++) {
            bf16x8 af, bfr[4];
            af = *(const bf16x8*)&fsm[(wm * 16 + r) * 264 + k0 + h * 32 + q * 8];
            #pragma unroll
            for (int j = 0; j < 4; j++)
                bfr[j] = *(const bf16x8*)(Bt +
                    (size_t)(wn * 64 + j * 16 + r) * C2 + k0 + h * 32 + q * 8);
            #pragma unroll
            for (int j = 0; j < 4; j++)
                acc[j] = __builtin_amdgcn_mfma_f32_16x16x32_bf16(
                    af, bfr[j], acc[j], 0, 0, 0);
        }
    }
    __syncthreads();   // all feat reads done -> safe to alias STF onto fsm

    // epilogue: stage fp32 tile in aliased LDS, then full-line float4 flush
    float* STF = (float*)fsm;              // [32][132]
    #pragma unroll
    for (int j = 0; j < 4; j++) {
        const int ch = wn * 64 + j * 16 + r;
        const float bo = bias[ch];
        const int mb = wm * 16 + q * 4;
        #pragma unroll
        for (int p = 0; p < 4; p++)
            STF[(mb + p) * 132 + ch] = acc[j][p] + bo;
    }
    __syncthreads();
    #pragma unroll
    for (int i = 0; i < 4; i++) {          // 32x128 fp32 = 1024 float4
        int idx = tid + i * 256;
        int row = idx >> 5, c4 = (idx & 31) * 4;
        if (m0 + row < N)
            *(float4*)(Cf + (size_t)(m0 + row) * C_OUT + c4) =
                *(const float4*)&STF[row * 132 + c4];
    }
}

extern "C" void kernel_launch(void* const* d_in, const int* in_sizes, int n_in,
                              void* d_out, int out_size, void* d_ws, size_t ws_size,
                              hipStream_t stream)
{
    const float* features = (const float*)d_in[0];
    const int*   nidx     = (const int*)d_in[1];
    const float* W1       = (const float*)d_in[2];
    const float* b1       = (const float*)d_in[3];
    const float* gamma    = (const float*)d_in[4];
    const float* beta     = (const float*)d_in[5];
    const float* mean     = (const float*)d_in[6];
    const float* var      = (const float*)d_in[7];
    const float* Ws       = (const float*)d_in[8];
    const float* Wm       = (const float*)d_in[9];
    const float* bm       = (const float*)d_in[10];
    float* out = (float*)d_out;

    const int N = in_sizes[0] / C_IN;   // 50000

    u16* packed = (u16*)d_ws;                      // N x 512 interleaved pairs
    u16* W1t    = packed + (size_t)N * 512;        // 256 x 128
    u16* Wst    = W1t + 256 * 128;                 // 256 x 256
    u16* Wmt    = Wst + 256 * 256;                 // 128 x 256
    float4* bnp = (float4*)(Wmt + 128 * 256);      // 256 folded BN params

    prep_k<<<dim3(256, 4), 256, 0, stream>>>(W1, Ws, Wm, b1, gamma, beta,
                                             mean, var, W1t, Wst, Wmt, bnp);

    const int MT = (N + 63) / 64;        // 782
    const int GT = (N + PTS - 1) / PTS;  // 1563

    mlp_k<<<MT, 256, 0, stream>>>(features, W1t, Wst, bnp, packed, N);
    gather_out_k<<<GT, 256, 0, stream>>>(packed, nidx, Wmt, bm, out, N);
}